// Round 12
// baseline (37.112 us; speedup 1.0000x reference)
//
#include <hip/hip_runtime.h>

#define N_IN   4096
#define N_NPB  64
#define COLS   16384
#define BATCH  128

typedef unsigned int       uint;
typedef unsigned short     ushort;
typedef unsigned long long u64;
typedef __attribute__((ext_vector_type(2))) _Float16 h2;

// ---------------------------------------------------------------------------
// ws layout:
//   [0,    1 MiB)  xTh : f16 row-major [4096 rows][128 batches]   (L2 path)
//   [1 MiB,2 MiB)  xT4 : f16 slice-major [32 slices][4096 rows][4] (LDS path)
//   [2 MiB,6 MiB)  pku : uint [64 k][16384 c] = (row << 16) | f16bits(w_eff)
// ---------------------------------------------------------------------------

static __device__ __forceinline__ ushort f16bits(float v) {
  return __builtin_bit_cast(ushort, (_Float16)v);
}

// keepmask + pack for k-group [KB, KB+16): keep iff no later k' duplicates.
template <int KB>
static __device__ __forceinline__ void keep_pk(
    const int* __restrict__ ip, const float* __restrict__ wp,
    uint* __restrict__ pkout) {
  int  g[16];
  uint m[16];
#pragma unroll
  for (int j = 0; j < 16; ++j) { g[j] = ip[(KB + j) * COLS]; m[j] = 0xffffffffu; }
#pragma unroll
  for (int j = 0; j < 16; ++j)
#pragma unroll
    for (int kp = j + 1; kp < 16; ++kp)
      m[j] = min(m[j], (uint)(g[j] ^ g[kp]));
#pragma unroll 4
  for (int kp = KB + 16; kp < 64; ++kp) {
    const int vk = ip[kp * COLS];
#pragma unroll
    for (int j = 0; j < 16; ++j) m[j] = min(m[j], (uint)(g[j] ^ vk));
  }
#pragma unroll
  for (int j = 0; j < 16; ++j) {
    const float wv = (m[j] != 0u) ? wp[(KB + j) * COLS] : 0.0f;
    pkout[(KB + j) * COLS] = ((uint)g[j] << 16) | (uint)f16bits(wv);
  }
}

// Prep: [0,512) transpose x -> xTh AND xT4; [512,768) keepmask+pack;
// [768,1024) zero d_out (needed because main accumulates via atomicAdd).
__global__ __launch_bounds__(256, 4) void prep_kernel(
    const float* __restrict__ x, const int* __restrict__ idx,
    const float* __restrict__ w, ushort* __restrict__ xTh,
    ushort* __restrict__ xT4, uint* __restrict__ pku,
    float4* __restrict__ out4) {
  const int bid = blockIdx.x;
  const int tid = threadIdx.x;
  if (bid < 512) {
    __shared__ float tile[32][33];
    const int i0 = (bid & 127) * 32;
    const int b0 = (bid >> 7) * 32;
    const int tx = tid & 31;
    const int ty = tid >> 5;    // 0..7
#pragma unroll
    for (int j = 0; j < 32; j += 8)
      tile[ty + j][tx] = x[(b0 + ty + j) * N_IN + i0 + tx];
    __syncthreads();
#pragma unroll
    for (int j = 0; j < 32; j += 8) {
      const int b = b0 + tx, i = i0 + ty + j;
      const ushort hv = f16bits(tile[tx][ty + j]);
      xTh[i * BATCH + b] = hv;                           // row-major
      xT4[((b >> 2) << 14) + (i << 2) + (b & 3)] = hv;   // slice-major
    }
  } else if (bid < 768) {
    const int kg = __builtin_amdgcn_readfirstlane(tid >> 6);  // wave-uniform
    const int c  = (bid - 512) * 64 + (tid & 63);
    if      (kg == 0) keep_pk<0 >(idx + c, w + c, pku + c);
    else if (kg == 1) keep_pk<16>(idx + c, w + c, pku + c);
    else if (kg == 2) keep_pk<32>(idx + c, w + c, pku + c);
    else              keep_pk<48>(idx + c, w + c, pku + c);
  } else {
    // zero 8 MiB of out: 256 blocks x 2048 float4 x 16 B = 8 MiB exactly.
    const int z = bid - 768;
    float4 zv; zv.x = zv.y = zv.z = zv.w = 0.0f;
    for (int i = tid; i < 2048; i += 256) out4[z * 2048 + i] = zv;
  }
}

// ---------------------------------------------------------------------------
// Main, heterogeneous: even bid -> L2-gather path (k=0..31, 16 cols, all 128
// batches); odd bid -> LDS-gather path (k=32..63, 512-col range, 4-batch
// slice). Interleaving keeps both block types co-resident per CU so the
// TA/L2 pipe and the DS pipe run CONCURRENTLY. Each (b,c) cell receives
// exactly 2 atomicAdd contributions onto a zeroed out -> deterministic
// (fp add is commutative).
// ---------------------------------------------------------------------------
__global__ __launch_bounds__(512, 8) void main_kernel(
    const uint* __restrict__ pku, const ushort* __restrict__ xTh,
    const ushort* __restrict__ xT4, float* __restrict__ out) {
  __shared__ __align__(16) char smem[33024];

  const int bid = blockIdx.x;
  const int tid = threadIdx.x;

  if ((bid & 1) == 0) {
    // ======== A: L2-gather, k = 0..31 ========
    u64   (*pk)[16]       = reinterpret_cast<u64(*)[16]>(smem);          // 4 KB
    float (*res)[16][132] = reinterpret_cast<float(*)[16][132]>(smem + 4096);
    const int c0 = (bid >> 1) * 16;

    {  // stage packed entries: 512 threads = 32 k x 16 c
      const int cl = tid & 15, k = tid >> 4;
      const uint e  = pku[k * COLS + c0 + cl];
      const uint wb = e & 0xffffu;
      pk[k][cl] = ((u64)((wb << 16) | wb) << 32) | (u64)((e >> 16) << 8);
    }
    __syncthreads();

    const int wave  = tid >> 6;
    const int khalf = wave >> 2;       // 0: k 0..15, 1: k 16..31
    const int lane  = tid & 63;
    const int g     = lane >> 4;
    const int b8    = lane & 15;
    const int cl    = (wave & 3) * 4 + g;

    const char* xb = (const char*)xTh;
    const uint  bo = (uint)b8 * 16;
    const int   kb = khalf * 16;

    h2 a0 = (h2)0.0f, a1 = (h2)0.0f, a2 = (h2)0.0f, a3 = (h2)0.0f;
#pragma unroll
    for (int kk = 0; kk < 16; ++kk) {
      const u64  e   = pk[kb + kk][cl];            // ds_read_b64, broadcast
      const uint off = (uint)e + bo;
      const h2   wh  = __builtin_bit_cast(h2, (uint)(e >> 32));
      const uint4 u  = *(const uint4*)(xb + off);  // 8 f16 batches
      a0 += __builtin_bit_cast(h2, u.x) * wh;
      a1 += __builtin_bit_cast(h2, u.y) * wh;
      a2 += __builtin_bit_cast(h2, u.z) * wh;
      a3 += __builtin_bit_cast(h2, u.w) * wh;
    }
    {
      float* r = &res[khalf][cl][b8 * 8];
      r[0] = (float)a0.x; r[1] = (float)a0.y;
      r[2] = (float)a1.x; r[3] = (float)a1.y;
      r[4] = (float)a2.x; r[5] = (float)a2.y;
      r[6] = (float)a3.x; r[7] = (float)a3.y;
    }
    __syncthreads();

    for (int e2 = tid; e2 < BATCH * 16; e2 += 512) {
      const int b = e2 >> 4, cc = e2 & 15;
      atomicAdd(&out[b * COLS + c0 + cc], res[0][cc][b] + res[1][cc][b]);
    }
  } else {
    // ======== B: LDS-gather, k = 32..63 ========
    ushort* xls = reinterpret_cast<ushort*>(smem);   // 32 KB slice
    const int b2   = bid >> 1;
    const int r    = b2 & 31;          // col-range (XCD-pinned-ish)
    const int s    = b2 >> 5;          // 4-batch slice
    const int wave = tid >> 6;
    const int lane = tid & 63;
    const int c    = r * 512 + wave * 64 + lane;

    {  // stage slice s (32 KB) via global_load_lds, 16 B/lane
      const ushort* src = xT4 + (s << 14);
#pragma unroll
      for (int t = 0; t < 4; ++t) {
        const int ub = (t * 8 + wave) * 512;         // wave-uniform base
        __builtin_amdgcn_global_load_lds(
            (const __attribute__((address_space(1))) void*)(src + ub + lane * 8),
            (__attribute__((address_space(3))) void*)(xls + ub), 16, 0, 0);
      }
    }
    __syncthreads();

    const uint* pc = pku + 32 * COLS + c;
    const char* xb = (const char*)xls;
    h2 a0 = (h2)0.0f, a1 = (h2)0.0f, a2 = (h2)0.0f, a3 = (h2)0.0f;
#pragma unroll
    for (int k = 0; k < 32; k += 2) {
      const uint e0 = pc[k * COLS];                  // coalesced, L2-hot
      const uint e1 = pc[(k + 1) * COLS];
      const uint o0 = (e0 >> 16) << 3;
      const uint o1 = (e1 >> 16) << 3;
      const uint w0 = e0 & 0xffffu, w1 = e1 & 0xffffu;
      const h2 wh0 = __builtin_bit_cast(h2, (w0 << 16) | w0);
      const h2 wh1 = __builtin_bit_cast(h2, (w1 << 16) | w1);
      const uint2 u0 = *(const uint2*)(xb + o0);     // ds_read_b64
      const uint2 u1 = *(const uint2*)(xb + o1);
      a0 += __builtin_bit_cast(h2, u0.x) * wh0;
      a1 += __builtin_bit_cast(h2, u0.y) * wh0;
      a2 += __builtin_bit_cast(h2, u1.x) * wh1;
      a3 += __builtin_bit_cast(h2, u1.y) * wh1;
    }

    atomicAdd(&out[(s * 4 + 0) * COLS + c], (float)a0.x + (float)a2.x);
    atomicAdd(&out[(s * 4 + 1) * COLS + c], (float)a0.y + (float)a2.y);
    atomicAdd(&out[(s * 4 + 2) * COLS + c], (float)a1.x + (float)a3.x);
    atomicAdd(&out[(s * 4 + 3) * COLS + c], (float)a1.y + (float)a3.y);
  }
}

extern "C" void kernel_launch(void* const* d_in, const int* in_sizes, int n_in,
                              void* d_out, int out_size, void* d_ws, size_t ws_size,
                              hipStream_t stream) {
  const float* x   = (const float*)d_in[0];
  const float* w   = (const float*)d_in[1];
  const int*   idx = (const int*)d_in[2];
  float* out = (float*)d_out;

  char* ws = (char*)d_ws;
  ushort* xTh = (ushort*)(ws);
  ushort* xT4 = (ushort*)(ws + (1u << 20));
  uint*   pku = (uint*)(ws + (2u << 20));

  hipLaunchKernelGGL(prep_kernel, dim3(1024), dim3(256), 0, stream,
                     x, idx, w, xTh, xT4, pku, (float4*)out);
  hipLaunchKernelGGL(main_kernel, dim3(2048), dim3(512), 0, stream,
                     pku, xTh, xT4, out);
}

// Round 13
// 31.823 us; speedup vs baseline: 1.1662x; 1.1662x over previous
//
#include <hip/hip_runtime.h>

#define N_IN   4096
#define N_NPB  64
#define COLS   16384
#define BATCH  128

typedef unsigned int       uint;
typedef unsigned short     ushort;
typedef unsigned long long u64;
typedef __attribute__((ext_vector_type(2))) _Float16 h2;

// ---------------------------------------------------------------------------
// ws layout:
//   [0,    1 MiB)  xTh : f16 row-major [4096 rows][128 batches]   (L2 path)
//   [1 MiB,2 MiB)  xT4 : f16 slice-major [32 slices][4096 rows][4] (LDS path)
//   [2 MiB,6 MiB)  pku : uint [64 k][16384 c] = (row << 16) | f16bits(w_eff)
// ---------------------------------------------------------------------------

static __device__ __forceinline__ ushort f16bits(float v) {
  return __builtin_bit_cast(ushort, (_Float16)v);
}

// keepmask + pack for k-group [KB, KB+16): keep iff no later k' duplicates.
template <int KB>
static __device__ __forceinline__ void keep_pk(
    const int* __restrict__ ip, const float* __restrict__ wp,
    uint* __restrict__ pkout) {
  int  g[16];
  uint m[16];
#pragma unroll
  for (int j = 0; j < 16; ++j) { g[j] = ip[(KB + j) * COLS]; m[j] = 0xffffffffu; }
#pragma unroll
  for (int j = 0; j < 16; ++j)
#pragma unroll
    for (int kp = j + 1; kp < 16; ++kp)
      m[j] = min(m[j], (uint)(g[j] ^ g[kp]));
#pragma unroll 4
  for (int kp = KB + 16; kp < 64; ++kp) {
    const int vk = ip[kp * COLS];
#pragma unroll
    for (int j = 0; j < 16; ++j) m[j] = min(m[j], (uint)(g[j] ^ vk));
  }
#pragma unroll
  for (int j = 0; j < 16; ++j) {
    const float wv = (m[j] != 0u) ? wp[(KB + j) * COLS] : 0.0f;
    pkout[(KB + j) * COLS] = ((uint)g[j] << 16) | (uint)f16bits(wv);
  }
}

// Prep: [0,512) transpose x -> xTh AND xT4; [512,768) keepmask+pack.
__global__ __launch_bounds__(256, 4) void prep_kernel(
    const float* __restrict__ x, const int* __restrict__ idx,
    const float* __restrict__ w, ushort* __restrict__ xTh,
    ushort* __restrict__ xT4, uint* __restrict__ pku) {
  const int bid = blockIdx.x;
  const int tid = threadIdx.x;
  if (bid < 512) {
    __shared__ float tile[32][33];
    const int i0 = (bid & 127) * 32;
    const int b0 = (bid >> 7) * 32;
    const int tx = tid & 31;
    const int ty = tid >> 5;    // 0..7
#pragma unroll
    for (int j = 0; j < 32; j += 8)
      tile[ty + j][tx] = x[(b0 + ty + j) * N_IN + i0 + tx];
    __syncthreads();
#pragma unroll
    for (int j = 0; j < 32; j += 8) {
      const int b = b0 + tx, i = i0 + ty + j;
      const ushort hv = f16bits(tile[tx][ty + j]);
      xTh[i * BATCH + b] = hv;                           // row-major
      xT4[((b >> 2) << 14) + (i << 2) + (b & 3)] = hv;   // slice-major
    }
  } else {
    const int kg = __builtin_amdgcn_readfirstlane(tid >> 6);  // wave-uniform
    const int c  = (bid - 512) * 64 + (tid & 63);
    if      (kg == 0) keep_pk<0 >(idx + c, w + c, pku + c);
    else if (kg == 1) keep_pk<16>(idx + c, w + c, pku + c);
    else if (kg == 2) keep_pk<32>(idx + c, w + c, pku + c);
    else              keep_pk<48>(idx + c, w + c, pku + c);
  }
}

// ---------------------------------------------------------------------------
// Main, heterogeneous by COLUMN split (no atomics — each out cell written
// exactly once):
//   even bid -> L2-gather path: cols [0, 8192), full k, full 128 batches
//               (verified R6 block structure, plain stores)
//   odd bid  -> LDS-gather path: cols [8192, 16384), full k, 4-batch slice
//               (verified R10 block structure)
// Parity interleave co-locates both types per CU so the TA/L1/L2 pipe and
// the DS pipe run concurrently; each path's gather volume is halved.
// ---------------------------------------------------------------------------
__global__ __launch_bounds__(512, 8) void main_kernel(
    const uint* __restrict__ pku, const ushort* __restrict__ xTh,
    const ushort* __restrict__ xT4, float* __restrict__ out) {
  __shared__ __align__(16) char smem[33024];

  const int bid = blockIdx.x;
  const int tid = threadIdx.x;

  if ((bid & 1) == 0) {
    // ======== A: L2-gather, cols [0, 8192), k = 0..63 ========
    u64   (*pk)[16]       = reinterpret_cast<u64(*)[16]>(smem);          // 8 KB
    float (*res)[16][132] = reinterpret_cast<float(*)[16][132]>(smem + 8192);
    const int c0 = (bid >> 1) * 16;

    {  // stage packed entries: 64 k x 16 c = 1024, 2 per thread
      const int cl = tid & 15;
      const int k0 = tid >> 4;          // 0..31
#pragma unroll
      for (int p = 0; p < 2; ++p) {
        const int k = k0 + p * 32;
        const uint e  = pku[k * COLS + c0 + cl];
        const uint wb = e & 0xffffu;
        pk[k][cl] = ((u64)((wb << 16) | wb) << 32) | (u64)((e >> 16) << 8);
      }
    }
    __syncthreads();

    const int wave  = tid >> 6;
    const int khalf = wave >> 2;       // 0: k 0..31, 1: k 32..63
    const int lane  = tid & 63;
    const int g     = lane >> 4;
    const int b8    = lane & 15;
    const int cl    = (wave & 3) * 4 + g;

    const char* xb = (const char*)xTh;
    const uint  bo = (uint)b8 * 16;
    const int   kb = khalf * 32;

    h2 a0 = (h2)0.0f, a1 = (h2)0.0f, a2 = (h2)0.0f, a3 = (h2)0.0f;
#pragma unroll
    for (int kk = 0; kk < 32; ++kk) {
      const u64  e   = pk[kb + kk][cl];            // ds_read_b64, broadcast
      const uint off = (uint)e + bo;
      const h2   wh  = __builtin_bit_cast(h2, (uint)(e >> 32));
      const uint4 u  = *(const uint4*)(xb + off);  // 8 f16 batches
      a0 += __builtin_bit_cast(h2, u.x) * wh;
      a1 += __builtin_bit_cast(h2, u.y) * wh;
      a2 += __builtin_bit_cast(h2, u.z) * wh;
      a3 += __builtin_bit_cast(h2, u.w) * wh;
    }
    {
      float* r = &res[khalf][cl][b8 * 8];
      r[0] = (float)a0.x; r[1] = (float)a0.y;
      r[2] = (float)a1.x; r[3] = (float)a1.y;
      r[4] = (float)a2.x; r[5] = (float)a2.y;
      r[6] = (float)a3.x; r[7] = (float)a3.y;
    }
    __syncthreads();

    for (int e2 = tid; e2 < BATCH * 16; e2 += 512) {
      const int b = e2 >> 4, cc = e2 & 15;
      out[b * COLS + c0 + cc] = res[0][cc][b] + res[1][cc][b];
    }
  } else {
    // ======== B: LDS-gather, cols [8192, 16384), k = 0..63 ========
    ushort* xls = reinterpret_cast<ushort*>(smem);   // 32 KB slice
    const int b2   = bid >> 1;
    const int r    = b2 & 15;          // col-range within upper half
    const int s    = b2 >> 4;          // 4-batch slice (0..31)
    const int wave = tid >> 6;
    const int lane = tid & 63;
    const int c    = 8192 + r * 512 + wave * 64 + lane;

    {  // stage slice s (32 KB) via global_load_lds, 16 B/lane
      const ushort* src = xT4 + (s << 14);
#pragma unroll
      for (int t = 0; t < 4; ++t) {
        const int ub = (t * 8 + wave) * 512;         // wave-uniform base
        __builtin_amdgcn_global_load_lds(
            (const __attribute__((address_space(1))) void*)(src + ub + lane * 8),
            (__attribute__((address_space(3))) void*)(xls + ub), 16, 0, 0);
      }
    }
    __syncthreads();

    const uint* pc = pku + c;
    const char* xb = (const char*)xls;
    h2 a0 = (h2)0.0f, a1 = (h2)0.0f, a2 = (h2)0.0f, a3 = (h2)0.0f;
#pragma unroll
    for (int k = 0; k < N_NPB; k += 2) {
      const uint e0 = pc[k * COLS];                  // coalesced, L2-hot
      const uint e1 = pc[(k + 1) * COLS];
      const uint o0 = (e0 >> 16) << 3;
      const uint o1 = (e1 >> 16) << 3;
      const uint w0 = e0 & 0xffffu, w1 = e1 & 0xffffu;
      const h2 wh0 = __builtin_bit_cast(h2, (w0 << 16) | w0);
      const h2 wh1 = __builtin_bit_cast(h2, (w1 << 16) | w1);
      const uint2 u0 = *(const uint2*)(xb + o0);     // ds_read_b64
      const uint2 u1 = *(const uint2*)(xb + o1);
      a0 += __builtin_bit_cast(h2, u0.x) * wh0;
      a1 += __builtin_bit_cast(h2, u0.y) * wh0;
      a2 += __builtin_bit_cast(h2, u1.x) * wh1;
      a3 += __builtin_bit_cast(h2, u1.y) * wh1;
    }

    out[(s * 4 + 0) * COLS + c] = (float)a0.x + (float)a2.x;
    out[(s * 4 + 1) * COLS + c] = (float)a0.y + (float)a2.y;
    out[(s * 4 + 2) * COLS + c] = (float)a1.x + (float)a3.x;
    out[(s * 4 + 3) * COLS + c] = (float)a1.y + (float)a3.y;
  }
}

extern "C" void kernel_launch(void* const* d_in, const int* in_sizes, int n_in,
                              void* d_out, int out_size, void* d_ws, size_t ws_size,
                              hipStream_t stream) {
  const float* x   = (const float*)d_in[0];
  const float* w   = (const float*)d_in[1];
  const int*   idx = (const int*)d_in[2];
  float* out = (float*)d_out;

  char* ws = (char*)d_ws;
  ushort* xTh = (ushort*)(ws);
  ushort* xT4 = (ushort*)(ws + (1u << 20));
  uint*   pku = (uint*)(ws + (2u << 20));

  hipLaunchKernelGGL(prep_kernel, dim3(768), dim3(256), 0, stream,
                     x, idx, w, xTh, xT4, pku);
  hipLaunchKernelGGL(main_kernel, dim3(1024), dim3(512), 0, stream,
                     pku, xTh, xT4, out);
}

// Round 14
// 23.812 us; speedup vs baseline: 1.5585x; 1.3364x over previous
//
#include <hip/hip_runtime.h>

#define N_IN   4096
#define N_NPB  64
#define COLS   16384
#define BATCH  128

typedef unsigned int       uint;
typedef unsigned short     ushort;
typedef unsigned long long u64;
typedef __attribute__((ext_vector_type(2))) _Float16 h2;

// ---------------------------------------------------------------------------
// ws layout:
//   [0,      1 MiB)       xTh  : f16 xT[4096][128] (ushort)
//   [1 MiB,  1 MiB+128 K) keep : ushort[COLS][4] = 64-bit keep mask per column
// ---------------------------------------------------------------------------

// keepmask helper: bit j (of this 16-k group) = 1 iff no later k' duplicates.
template <int KBASE>
static __device__ __forceinline__ uint compute_bits(const int* __restrict__ ip) {
  int v[64 - KBASE];
#pragma unroll
  for (int k = 0; k < 64 - KBASE; ++k) v[k] = ip[(KBASE + k) * COLS];
  uint bits = 0;
#pragma unroll
  for (int j = 0; j < 16; ++j) {
    uint m = 0xffffffffu;
#pragma unroll
    for (int kp = j + 1; kp < 64 - KBASE; ++kp)
      m = min(m, (uint)(v[j] ^ v[kp]));
    bits |= (m != 0u) ? (1u << j) : 0u;
  }
  return bits;
}

// Fused prep: blocks [0,512) transpose x -> f16 xT; blocks [512,768) keepmask.
__global__ __launch_bounds__(256, 4) void prep_kernel(
    const float* __restrict__ x, const int* __restrict__ idx,
    ushort* __restrict__ xTh, ushort* __restrict__ keep16) {
  const int bid = blockIdx.x;
  const int tid = threadIdx.x;
  if (bid < 512) {
    __shared__ float tile[32][33];
    const int i0 = (bid & 127) * 32;
    const int b0 = (bid >> 7) * 32;
    const int tx = tid & 31;
    const int ty = tid >> 5;    // 0..7
#pragma unroll
    for (int j = 0; j < 32; j += 8)
      tile[ty + j][tx] = x[(b0 + ty + j) * N_IN + i0 + tx];
    __syncthreads();
#pragma unroll
    for (int j = 0; j < 32; j += 8)
      xTh[(i0 + ty + j) * BATCH + b0 + tx] =
          __builtin_bit_cast(ushort, (_Float16)tile[tx][ty + j]);
  } else {
    const int kg = __builtin_amdgcn_readfirstlane(tid >> 6);  // wave-uniform
    const int c  = (bid - 512) * 64 + (tid & 63);
    const int* ip = idx + c;
    uint bits;
    if      (kg == 0) bits = compute_bits<0>(ip);
    else if (kg == 1) bits = compute_bits<16>(ip);
    else if (kg == 2) bits = compute_bits<32>(ip);
    else              bits = compute_bits<48>(ip);
    keep16[c * 4 + kg] = (ushort)bits;
  }
}

// ---------------------------------------------------------------------------
// Main: out[b,c] = sum_k wk * xTh[idx[k][c]][b]
// Split-k: 512 threads = 8 waves. Waves 0-3 do k=0..31, waves 4-7 k=32..63,
// both for the block's 16 columns; partials combined in LDS at the end.
// Within a wave-quad: g=lane>>4 (column of 4), b8=lane&15 (batch octet,
// one dwordx4 = 8 f16 batches -> full 256 B row per 16-lane group).
// Grid 1024 -> 4 blocks/CU x 8 waves = 32 waves/CU (full occupancy).
// ---------------------------------------------------------------------------
__global__ __launch_bounds__(512, 8) void branch_main_kernel(
    const float* __restrict__ w, const int* __restrict__ idx,
    const u64* __restrict__ keep, const ushort* __restrict__ xTh,
    float* __restrict__ out) {
  __shared__ u64   pk[N_NPB][16];
  __shared__ float res[2][16][132];   // [khalf][col][batch], 132: 16B-aligned rows

  const int tid = threadIdx.x;
  const int c0  = blockIdx.x * 16;

  // Stage packed (offset | dup'd f16 weight) entries; 2 per thread, coalesced.
  {
    const int cl = tid & 15;
    const int k0 = (tid >> 4) * 2;
    const u64 km = keep[c0 + cl];
#pragma unroll
    for (int p = 0; p < 2; ++p) {
      const int k   = k0 + p;
      const int row = idx[k * COLS + c0 + cl];
      float wv      = w[k * COLS + c0 + cl];
      wv = ((km >> k) & 1ull) ? wv : 0.0f;
      const uint hb = (uint)__builtin_bit_cast(ushort, (_Float16)wv);
      pk[k][cl] = ((u64)((hb << 16) | hb) << 32) | ((u64)((uint)row << 8));
    }
  }
  __syncthreads();

  const int wave  = tid >> 6;
  const int khalf = wave >> 2;        // 0: k=0..31, 1: k=32..63
  const int lane  = tid & 63;
  const int g     = lane >> 4;
  const int b8    = lane & 15;
  const int cl    = (wave & 3) * 4 + g;

  const char* xb = (const char*)xTh;
  const uint  bo = (uint)b8 * 16;
  const int   kb = khalf * 32;

  h2 a0 = (h2)0.0f, a1 = (h2)0.0f, a2 = (h2)0.0f, a3 = (h2)0.0f;
#pragma unroll
  for (int kk = 0; kk < 32; ++kk) {
    const u64  e   = pk[kb + kk][cl];                 // ds_read_b64, broadcast
    const uint off = (uint)e + bo;                    // one v_add_u32
    const h2   wh  = __builtin_bit_cast(h2, (uint)(e >> 32));
    const uint4 u  = *(const uint4*)(xb + off);       // 8 f16 batches
    a0 += __builtin_bit_cast(h2, u.x) * wh;           // v_pk_fma_f16
    a1 += __builtin_bit_cast(h2, u.y) * wh;
    a2 += __builtin_bit_cast(h2, u.z) * wh;
    a3 += __builtin_bit_cast(h2, u.w) * wh;
  }

  // Stage partials: 8 consecutive floats per lane -> 2x ds_write_b128.
  {
    float* r = &res[khalf][cl][b8 * 8];
    r[0] = (float)a0.x; r[1] = (float)a0.y;
    r[2] = (float)a1.x; r[3] = (float)a1.y;
    r[4] = (float)a2.x; r[5] = (float)a2.y;
    r[6] = (float)a3.x; r[7] = (float)a3.y;
  }
  __syncthreads();

  // Combine split-k partials + coalesced output.
  for (int e = tid; e < BATCH * 16; e += 512) {
    const int b = e >> 4, cc = e & 15;
    out[b * COLS + c0 + cc] = res[0][cc][b] + res[1][cc][b];
  }
}

extern "C" void kernel_launch(void* const* d_in, const int* in_sizes, int n_in,
                              void* d_out, int out_size, void* d_ws, size_t ws_size,
                              hipStream_t stream) {
  const float* x   = (const float*)d_in[0];
  const float* w   = (const float*)d_in[1];
  const int*   idx = (const int*)d_in[2];
  float* out = (float*)d_out;

  char* ws = (char*)d_ws;
  ushort* xTh    = (ushort*)(ws);
  ushort* keep16 = (ushort*)(ws + (1u << 20));
  u64*    keep   = (u64*)(ws + (1u << 20));

  hipLaunchKernelGGL(prep_kernel, dim3(512 + COLS / 64), dim3(256), 0, stream,
                     x, idx, xTh, keep16);
  hipLaunchKernelGGL(branch_main_kernel, dim3(COLS / 16), dim3(512), 0, stream,
                     w, idx, keep, xTh, out);
}